// Round 6
// baseline (148.853 us; speedup 1.0000x reference)
//
#include <hip/hip_runtime.h>

// Problem constants (match reference).
#define N_TOK   262144
#define D       256
#define NSEQ    512
#define MAX_LEN 640

#define CHUNK   256                  // rows per rank block
#define NBLK    (N_TOK / CHUNK)      // 1024
#define SEG     16                   // chunks per scan segment
#define NSEGS   (NBLK / SEG)         // 64
#define NSLOTS  (NSEQ * MAX_LEN)     // 327680
#define NWAVES  8192                 // gather: 2048 blocks x 4 waves
#define ITERS   (NSLOTS / NWAVES)    // 40

typedef float f32x4 __attribute__((ext_vector_type(4)));

// ---------------- Pass 1: per-chunk histogram + per-segment sum ----------------
__global__ __launch_bounds__(512) void k_count(const int* __restrict__ ids,
                                               int* __restrict__ counts,
                                               int* __restrict__ segsum) {
    __shared__ int h[SEG][NSEQ];     // 32 KB
    const int seg = blockIdx.x;      // [0, NSEGS)
    const int t   = threadIdx.x;     // [0, 512)
#pragma unroll
    for (int k = 0; k < SEG; ++k) h[k][t] = 0;
    __syncthreads();
    const int base = seg * (SEG * CHUNK);   // 4096 ids per segment
#pragma unroll
    for (int k = 0; k < 8; ++k) {
        const int i  = t + 512 * k;         // [0, 4096)
        const int id = ids[base + i];
        atomicAdd(&h[i >> 8][id], 1);       // chunk-local histogram
    }
    __syncthreads();
    int acc = 0;
#pragma unroll
    for (int k = 0; k < SEG; ++k) {
        const int c = h[k][t];
        counts[(seg * SEG + k) * NSEQ + t] = c;
        acc += c;
    }
    segsum[seg * NSEQ + t] = acc;
}

// ---------------- Pass 2: per-chunk exclusive prefix + totals ----------------
__global__ __launch_bounds__(512) void k_expand2(const int* __restrict__ counts,
                                                 const int* __restrict__ segsum,
                                                 int* __restrict__ prefix,
                                                 int* __restrict__ totals) {
    const int seg = blockIdx.x;
    const int t   = threadIdx.x;     // sequence id lane
    int acc = 0;
    for (int g = 0; g < seg; ++g) acc += segsum[g * NSEQ + t];
#pragma unroll
    for (int k = 0; k < SEG; ++k) {
        const int b = seg * SEG + k;
        prefix[b * NSEQ + t] = acc;
        acc += counts[b * NSEQ + t];
    }
    if (seg == NSEGS - 1) totals[t] = acc;
}

// ---------------- Pass 3: stable ranks -> scatter ROW INDICES (4 B each) ------
// Wave-histogram trick: rank = prefix + (count of my id in EARLIER waves, via
// per-wave LDS hist) + (count of earlier SAME-WAVE lanes, <=63-iter loop).
__global__ __launch_bounds__(256) void k_rankscat(const int* __restrict__ ids,
                                                  const int* __restrict__ prefix,
                                                  int* __restrict__ row_index) {
    __shared__ int lid[CHUNK];
    __shared__ int pre[NSEQ];
    __shared__ int wh[4][NSEQ];      // per-wave histograms, 8 KB
    const int b = blockIdx.x;
    const int t = threadIdx.x;

    lid[t]       = ids[b * CHUNK + t];
    pre[t]       = prefix[b * NSEQ + t];
    pre[t + 256] = prefix[b * NSEQ + t + 256];
#pragma unroll
    for (int k = 0; k < 8; ++k) wh[0][t + 256 * k & (4 * NSEQ - 1)] = 0;
    __syncthreads();

    const int w    = t >> 6;
    const int myid = lid[t];
    atomicAdd(&wh[w][myid], 1);
    __syncthreads();

    int r = 0;
    for (int ww = 0; ww < w; ++ww) r += wh[ww][myid];   // earlier waves
    for (int j = w << 6; j < t; ++j) r += (lid[j] == myid);  // same wave, stable
    r += pre[myid];
    if (r < MAX_LEN)                                    // drop OOB (JAX semantics)
        row_index[myid * MAX_LEN + r] = b * CHUNK + t;
}

// ---------------- Pass 4: globally-coherent gather + zero-fill + mask ---------
// One wave per slot, GRID-STRIDE: the 8192 active waves write one contiguous
// ~8 MB moving window (DRAM page-coherent). Valid slots gather a random 1 KB
// row with a nontemporal load (read-once stream, keep L2 for row_index/totals);
// empty slots take the wave-uniform else-branch and write zeros only.
__global__ __launch_bounds__(256) void k_gather(const float* __restrict__ batch,
                                                const int* __restrict__ row_index,
                                                const int* __restrict__ totals,
                                                float* __restrict__ padded,
                                                float* __restrict__ mask) {
    const int wid  = (blockIdx.x * 256 + threadIdx.x) >> 6;   // wave-uniform
    const int lane = threadIdx.x & 63;
#pragma unroll 8
    for (int i = 0; i < ITERS; ++i) {
        const int slot = wid + i * NWAVES;
        const int s    = slot / MAX_LEN;
        const int l    = slot - s * MAX_LEN;
        const int tot  = totals[s];                 // L2-hot broadcast
        f32x4 v = {0.f, 0.f, 0.f, 0.f};
        if (l < tot) {                              // wave-uniform branch
            const int r = row_index[slot];          // dense in slot order, L2
            v = __builtin_nontemporal_load(
                    (const f32x4*)(batch + (size_t)r * D) + lane);  // random 1 KB
        }
        __builtin_nontemporal_store(v, (f32x4*)(padded + (size_t)slot * D) + lane);
        if (lane == 0)
            __builtin_nontemporal_store((l >= tot) ? 1.0f : 0.0f, mask + slot);
    }
}

extern "C" void kernel_launch(void* const* d_in, const int* in_sizes, int n_in,
                              void* d_out, int out_size, void* d_ws, size_t ws_size,
                              hipStream_t stream) {
    const float* batch = (const float*)d_in[0];
    const int*   ids   = (const int*)d_in[1];

    float* padded = (float*)d_out;                        // [S, MAX_LEN, D]
    float* mask   = padded + (size_t)NSEQ * MAX_LEN * D;  // [S, MAX_LEN]

    int* ws        = (int*)d_ws;
    int* counts    = ws;                         // NBLK*NSEQ
    int* prefix    = counts + NBLK * NSEQ;       // NBLK*NSEQ
    int* segsum    = prefix + NBLK * NSEQ;       // NSEGS*NSEQ
    int* totals    = segsum + NSEGS * NSEQ;      // NSEQ
    int* row_index = totals + NSEQ;              // NSLOTS
    // row_index slots for padding positions are never written NOR dereferenced
    // (validity decided by totals before use) -> deterministic output regardless
    // of ws contents.

    k_count   <<<NSEGS, 512, 0, stream>>>(ids, counts, segsum);
    k_expand2 <<<NSEGS, 512, 0, stream>>>(counts, segsum, prefix, totals);
    k_rankscat<<<NBLK,  256, 0, stream>>>(ids, prefix, row_index);
    k_gather  <<<2048,  256, 0, stream>>>(batch, row_index, totals, padded, mask);
}

// Round 7
// 134.601 us; speedup vs baseline: 1.1059x; 1.1059x over previous
//
#include <hip/hip_runtime.h>

// Problem constants (match reference).
#define N_TOK   262144
#define D       256
#define NSEQ    512
#define MAX_LEN 640

#define CHUNK   256                  // rows per rank block
#define NBLK    (N_TOK / CHUNK)      // 1024
#define SEG     16                   // chunks per scan segment
#define NSEGS   (NBLK / SEG)         // 64
#define NSLOTS  (NSEQ * MAX_LEN)     // 327680
#define NWAVES  8192                 // gather: 2048 blocks x 4 waves
#define ITERS   (NSLOTS / NWAVES)    // 40

typedef float f32x4 __attribute__((ext_vector_type(4)));

// ---------------- Pass 1: histogram + per-segment sum + row_index zero-init ---
__global__ __launch_bounds__(512) void k_count(const int* __restrict__ ids,
                                               int* __restrict__ counts,
                                               int* __restrict__ segsum,
                                               int* __restrict__ row_index) {
    __shared__ int h[SEG][NSEQ];     // 32 KB
    const int seg = blockIdx.x;      // [0, NSEGS)
    const int t   = threadIdx.x;     // [0, 512)

    // zero-init row_index so k_gather can load branchlessly (empty slots -> row 0)
    for (int i = seg * 512 + t; i < NSLOTS; i += NSEGS * 512) row_index[i] = 0;

#pragma unroll
    for (int k = 0; k < SEG; ++k) h[k][t] = 0;
    __syncthreads();
    const int base = seg * (SEG * CHUNK);   // 4096 ids per segment
#pragma unroll
    for (int k = 0; k < 8; ++k) {
        const int i  = t + 512 * k;         // [0, 4096)
        const int id = ids[base + i];
        atomicAdd(&h[i >> 8][id], 1);       // chunk-local histogram
    }
    __syncthreads();
    int acc = 0;
#pragma unroll
    for (int k = 0; k < SEG; ++k) {
        const int c = h[k][t];
        counts[(seg * SEG + k) * NSEQ + t] = c;
        acc += c;
    }
    segsum[seg * NSEQ + t] = acc;
}

// ---------------- Pass 2: per-chunk exclusive prefix + totals ----------------
__global__ __launch_bounds__(512) void k_expand2(const int* __restrict__ counts,
                                                 const int* __restrict__ segsum,
                                                 int* __restrict__ prefix,
                                                 int* __restrict__ totals) {
    const int seg = blockIdx.x;
    const int t   = threadIdx.x;     // sequence id lane
    int acc = 0;
    for (int g = 0; g < seg; ++g) acc += segsum[g * NSEQ + t];
#pragma unroll
    for (int k = 0; k < SEG; ++k) {
        const int b = seg * SEG + k;
        prefix[b * NSEQ + t] = acc;
        acc += counts[b * NSEQ + t];
    }
    if (seg == NSEGS - 1) totals[t] = acc;
}

// ---------------- Pass 3: stable ranks -> scatter ROW INDICES (4 B each) ------
// Wave-histogram trick: rank = prefix + (count of my id in EARLIER waves, via
// per-wave LDS hist) + (count of earlier SAME-WAVE lanes, <=63-iter loop).
__global__ __launch_bounds__(256) void k_rankscat(const int* __restrict__ ids,
                                                  const int* __restrict__ prefix,
                                                  int* __restrict__ row_index) {
    __shared__ int lid[CHUNK];
    __shared__ int pre[NSEQ];
    __shared__ int wh[4][NSEQ];      // per-wave histograms, 8 KB
    const int b = blockIdx.x;
    const int t = threadIdx.x;

    lid[t]       = ids[b * CHUNK + t];
    pre[t]       = prefix[b * NSEQ + t];
    pre[t + 256] = prefix[b * NSEQ + t + 256];
#pragma unroll
    for (int k = 0; k < 8; ++k) ((int*)wh)[(t + 256 * k) & (4 * NSEQ - 1)] = 0;
    __syncthreads();

    const int w    = t >> 6;
    const int myid = lid[t];
    atomicAdd(&wh[w][myid], 1);
    __syncthreads();

    int r = 0;
    for (int ww = 0; ww < w; ++ww) r += wh[ww][myid];        // earlier waves
    for (int j = w << 6; j < t; ++j) r += (lid[j] == myid);  // same wave, stable
    r += pre[myid];
    if (r < MAX_LEN)                                    // drop OOB (JAX semantics)
        row_index[myid * MAX_LEN + r] = b * CHUNK + t;
}

// ---------------- Pass 4: globally-coherent gather + zero-fill + mask ---------
// ROUND-5 form (best measured): branchless, grid-stride (8192 waves move one
// contiguous ~8 MB write window), unconditional gather (empty slots re-read
// L2-hot row 0), NT stores only. unroll 4 keeps the write window narrow.
__global__ __launch_bounds__(256) void k_gather(const float* __restrict__ batch,
                                                const int* __restrict__ row_index,
                                                const int* __restrict__ totals,
                                                float* __restrict__ padded,
                                                float* __restrict__ mask) {
    const int wid  = (blockIdx.x * 256 + threadIdx.x) >> 6;   // [0, NWAVES)
    const int lane = threadIdx.x & 63;
#pragma unroll 4
    for (int i = 0; i < ITERS; ++i) {
        const int slot = wid + i * NWAVES;
        const int s    = slot / MAX_LEN;
        const int l    = slot - s * MAX_LEN;
        const int tot  = totals[s];                 // L2-hot broadcast
        const int r    = row_index[slot];           // coalesced across waves
        f32x4 v = ((const f32x4*)(batch + (size_t)r * D))[lane];  // random 1 KB
        if (l >= tot) v = (f32x4){0.f, 0.f, 0.f, 0.f};            // cndmask
        __builtin_nontemporal_store(v, (f32x4*)(padded + (size_t)slot * D) + lane);
        if (lane == 0)
            __builtin_nontemporal_store((l >= tot) ? 1.0f : 0.0f, mask + slot);
    }
}

extern "C" void kernel_launch(void* const* d_in, const int* in_sizes, int n_in,
                              void* d_out, int out_size, void* d_ws, size_t ws_size,
                              hipStream_t stream) {
    const float* batch = (const float*)d_in[0];
    const int*   ids   = (const int*)d_in[1];

    float* padded = (float*)d_out;                        // [S, MAX_LEN, D]
    float* mask   = padded + (size_t)NSEQ * MAX_LEN * D;  // [S, MAX_LEN]

    int* ws        = (int*)d_ws;
    int* counts    = ws;                         // NBLK*NSEQ
    int* prefix    = counts + NBLK * NSEQ;       // NBLK*NSEQ
    int* segsum    = prefix + NBLK * NSEQ;       // NSEGS*NSEQ
    int* totals    = segsum + NSEGS * NSEQ;      // NSEQ
    int* row_index = totals + NSEQ;              // NSLOTS
    // ws use ~5.6 MB; every word read is written earlier in the same call.

    k_count   <<<NSEGS, 512, 0, stream>>>(ids, counts, segsum, row_index);
    k_expand2 <<<NSEGS, 512, 0, stream>>>(counts, segsum, prefix, totals);
    k_rankscat<<<NBLK,  256, 0, stream>>>(ids, prefix, row_index);
    k_gather  <<<2048,  256, 0, stream>>>(batch, row_index, totals, padded, mask);
}